// Round 3
// baseline (199.301 us; speedup 1.0000x reference)
//
#include <hip/hip_runtime.h>
#include <hip/hip_bf16.h>

typedef __bf16 bf16x8_t __attribute__((ext_vector_type(8)));
typedef float  f32x4_t  __attribute__((ext_vector_type(4)));
typedef short  short8_t __attribute__((ext_vector_type(8)));
typedef short  short4_t __attribute__((ext_vector_type(4)));

#define NB   4
#define NH   16
#define SEQ  2048
#define HD   64
#define BQ   128   // q rows per block (2 fragment sets per wave)
#define BKV  64
#define LSTR 72    // LDS row stride in bf16 elems: 144B rows, 16B-aligned blocks

// masked score in base-2 domain: WHERE_CONST * log2(e)
#define MASK2 (-14426.950408889634f)
// softmax scale folded into Q: (1/sqrt(64)) * log2(e)
#define QSCL  (0.18033688011112042f)

// uniform swizzled LDS address (shorts): row*72 + ((blk ^ (row>>3)) & 7) * 8
__device__ __forceinline__ int swz(int rowi, int blk) {
    return rowi * LSTR + (((blk) ^ (rowi >> 3)) & 7) * 8;
}

__global__ void __launch_bounds__(256)
fa_fwd(const float* __restrict__ qg,
       const float* __restrict__ kg,
       const float* __restrict__ vg,
       float* __restrict__ outg) {
    __shared__ alignas(16) short k_lds[BKV * LSTR];   // K tile bf16 [kv][d], block-swizzled
    __shared__ alignas(16) short vt_lds[HD * LSTR];   // V^T tile bf16 [d][kv], block-swizzled
    __shared__ alignas(16) short p_lds[BQ * LSTR];    // P bf16 [q][kv], A rows 0-63, B rows 64-127

    const int tid  = threadIdx.x;
    const int wave = tid >> 6;
    const int lane = tid & 63;
    const int l16  = lane & 15;
    const int quad = lane >> 4;

    // grid: x = bh (64), y = q-block (16); y reversed so heaviest blocks dispatch first
    const int bh = blockIdx.x;
    const int qb = (int)gridDim.y - 1 - (int)blockIdx.y;
    const int q0 = qb * BQ;

    const size_t base = (size_t)bh * SEQ * HD;
    const float* qp = qg + base;
    const float* kp = kg + base;
    const float* vp = vg + base;

    // ---- Q fragments (B-operand in swapped QK^T): q=l16-row, d=quad*8+j ----
    bf16x8_t qfA0, qfA1, qfB0, qfB1;
    auto load_q = [&](int row, bf16x8_t& f0, bf16x8_t& f1) {
        const float* qr = qp + (size_t)row * HD;
        f32x4_t a0 = *(const f32x4_t*)(qr + quad * 8);
        f32x4_t a1 = *(const f32x4_t*)(qr + quad * 8 + 4);
        f32x4_t a2 = *(const f32x4_t*)(qr + 32 + quad * 8);
        f32x4_t a3 = *(const f32x4_t*)(qr + 32 + quad * 8 + 4);
        #pragma unroll
        for (int j = 0; j < 4; ++j) {
            f0[j]     = (__bf16)(a0[j] * QSCL);
            f0[4 + j] = (__bf16)(a1[j] * QSCL);
            f1[j]     = (__bf16)(a2[j] * QSCL);
            f1[4 + j] = (__bf16)(a3[j] * QSCL);
        }
    };
    load_q(q0 + wave * 16 + l16, qfA0, qfA1);
    load_q(q0 + 64 + wave * 16 + l16, qfB0, qfB1);

    f32x4_t oA[4], oB[4];
    const f32x4_t zero4 = {0.0f, 0.0f, 0.0f, 0.0f};
    #pragma unroll
    for (int c = 0; c < 4; ++c) { oA[c] = zero4; oB[c] = zero4; }
    float mA = MASK2, lA = 0.0f, mB = MASK2, lB = 0.0f;

    // ---- staging addressing: thread owns kv rows 4*sr..4*sr+3, d block d0..d0+3 ----
    const int sr = tid >> 4;      // 0..15
    const int cb = tid & 15;
    const int d0 = cb * 4;

    f32x4_t kreg[4], vreg[4];     // tile data in flight during compute

    auto issue = [&](int kt0) {
        const float* kr = kp + (size_t)(kt0 + 4 * sr) * HD + d0;
        const float* vr = vp + (size_t)(kt0 + 4 * sr) * HD + d0;
        #pragma unroll
        for (int i = 0; i < 4; ++i) {
            kreg[i] = *(const f32x4_t*)(kr + i * HD);
            vreg[i] = *(const f32x4_t*)(vr + i * HD);
        }
    };

    auto stage = [&]() {
        #pragma unroll
        for (int i = 0; i < 4; ++i) {
            const int r0 = 4 * sr + i;
            short4_t kw;
            #pragma unroll
            for (int j = 0; j < 4; ++j) kw[j] = __builtin_bit_cast(short, (__bf16)kreg[i][j]);
            *(short4_t*)&k_lds[swz(r0, cb >> 1) + (cb & 1) * 4] = kw;
        }
        #pragma unroll
        for (int j = 0; j < 4; ++j) {
            short4_t vw;
            #pragma unroll
            for (int i = 0; i < 4; ++i) vw[i] = __builtin_bit_cast(short, (__bf16)vreg[i][j]);
            *(short4_t*)&vt_lds[swz(d0 + j, sr >> 1) + (sr & 1) * 4] = vw;
        }
    };

    const int qloc = wave * 16 + l16;   // diag-tile local q row (same for A and B sets)

    // online softmax on 16 lane-local scores + P store (rows prow_)
    auto softmax_pstore = [&](const f32x4_t (&s)[4], float& m, float& l,
                              f32x4_t (&o)[4], bool diag, int prow_) {
        float sv[4][4];
        float vmax = MASK2;
        #pragma unroll
        for (int c = 0; c < 4; ++c) {
            #pragma unroll
            for (int r = 0; r < 4; ++r) {
                float x = s[c][r];
                if (diag && (c * 16 + quad * 4 + r > qloc)) x = MASK2;
                sv[c][r] = x;
                vmax = fmaxf(vmax, x);
            }
        }
        vmax = fmaxf(vmax, __shfl_xor(vmax, 16));
        vmax = fmaxf(vmax, __shfl_xor(vmax, 32));
        if (__any((int)(vmax > m))) {
            float mn = fmaxf(m, vmax);
            float a  = __builtin_amdgcn_exp2f(m - mn);   // arg <= 0
            m = mn;
            l *= a;
            float ar[4];
            #pragma unroll
            for (int r = 0; r < 4; ++r)
                ar[r] = __shfl(a, (lane & 48) | (quad * 4 + r));
            #pragma unroll
            for (int c = 0; c < 4; ++c)
                #pragma unroll
                for (int r = 0; r < 4; ++r)
                    o[c][r] *= ar[r];
        }
        float rs = 0.0f;
        #pragma unroll
        for (int c = 0; c < 4; ++c) {
            short4_t pw;
            #pragma unroll
            for (int r = 0; r < 4; ++r) {
                float p = __builtin_amdgcn_exp2f(sv[c][r] - m);  // arg <= 0
                rs += p;
                pw[r] = __builtin_bit_cast(short, (__bf16)p);
            }
            *(short4_t*)&p_lds[swz(prow_, 2 * c + (quad >> 1)) + (quad & 1) * 4] = pw;
        }
        rs += __shfl_xor(rs, 16);
        rs += __shfl_xor(rs, 32);
        l += rs;
    };

    issue(0);   // prologue: tile 0 in flight

    const int ntiles = 2 * qb + 2;
    for (int t = 0; t < ntiles; ++t) {
        const int kt0 = t * BKV;
        __syncthreads();            // A: prior iteration's LDS readers done
        stage();                    // regs (tile t) -> LDS, bf16 convert
        __syncthreads();            // B: staged tile visible
        if (t + 1 < ntiles) issue(kt0 + BKV);   // tile t+1 in flight during compute

        const bool doA   = (t < ntiles - 1);    // last tile fully masked for set A
        const bool diagA = (t == ntiles - 2);
        const bool diagB = (t == ntiles - 1);

        // ---- S^T = K Q^T : D[m=kv][n=q]; K-frag reads shared between A and B ----
        f32x4_t sA[4], sB[4];
        #pragma unroll
        for (int c = 0; c < 4; ++c) { sA[c] = zero4; sB[c] = zero4; }
        __builtin_amdgcn_s_setprio(1);
        #pragma unroll
        for (int c = 0; c < 4; ++c) {
            const int kvrow = c * 16 + l16;
            bf16x8_t kf0 = __builtin_bit_cast(bf16x8_t, *(const short8_t*)&k_lds[swz(kvrow, quad)]);
            bf16x8_t kf1 = __builtin_bit_cast(bf16x8_t, *(const short8_t*)&k_lds[swz(kvrow, quad + 4)]);
            if (doA) {
                sA[c] = __builtin_amdgcn_mfma_f32_16x16x32_bf16(kf0, qfA0, sA[c], 0, 0, 0);
                sA[c] = __builtin_amdgcn_mfma_f32_16x16x32_bf16(kf1, qfA1, sA[c], 0, 0, 0);
            }
            sB[c] = __builtin_amdgcn_mfma_f32_16x16x32_bf16(kf0, qfB0, sB[c], 0, 0, 0);
            sB[c] = __builtin_amdgcn_mfma_f32_16x16x32_bf16(kf1, qfB1, sB[c], 0, 0, 0);
        }
        __builtin_amdgcn_s_setprio(0);

        // ---- online softmax + P stores (A rows 0-63, B rows 64-127) ----
        const int prowA = wave * 16 + l16;
        if (doA) softmax_pstore(sA, mA, lA, oA, diagA, prowA);
        softmax_pstore(sB, mB, lB, oB, diagB, 64 + prowA);

        // NO barrier: P tiles written and read within the same wave (lgkmcnt orders)

        // ---- O += P V : V^T reads shared between A and B ----
        bf16x8_t pfA0, pfA1;
        if (doA) {
            pfA0 = __builtin_bit_cast(bf16x8_t, *(const short8_t*)&p_lds[swz(prowA, quad)]);
            pfA1 = __builtin_bit_cast(bf16x8_t, *(const short8_t*)&p_lds[swz(prowA, quad + 4)]);
        }
        bf16x8_t pfB0 = __builtin_bit_cast(bf16x8_t, *(const short8_t*)&p_lds[swz(64 + prowA, quad)]);
        bf16x8_t pfB1 = __builtin_bit_cast(bf16x8_t, *(const short8_t*)&p_lds[swz(64 + prowA, quad + 4)]);
        __builtin_amdgcn_s_setprio(1);
        #pragma unroll
        for (int c = 0; c < 4; ++c) {
            const int d = c * 16 + l16;
            bf16x8_t b0 = __builtin_bit_cast(bf16x8_t, *(const short8_t*)&vt_lds[swz(d, quad)]);
            bf16x8_t b1 = __builtin_bit_cast(bf16x8_t, *(const short8_t*)&vt_lds[swz(d, quad + 4)]);
            if (doA) {
                oA[c] = __builtin_amdgcn_mfma_f32_16x16x32_bf16(pfA0, b0, oA[c], 0, 0, 0);
                oA[c] = __builtin_amdgcn_mfma_f32_16x16x32_bf16(pfA1, b1, oA[c], 0, 0, 0);
            }
            oB[c] = __builtin_amdgcn_mfma_f32_16x16x32_bf16(pfB0, b0, oB[c], 0, 0, 0);
            oB[c] = __builtin_amdgcn_mfma_f32_16x16x32_bf16(pfB1, b1, oB[c], 0, 0, 0);
        }
        __builtin_amdgcn_s_setprio(0);
    }

    // ---- epilogue: O / l, fp32 store to out[b][q][h*64 + d] ----
    const int b = bh >> 4;
    const int h = bh & 15;
    auto store_o = [&](const f32x4_t (&o)[4], float l, int row_base) {
        #pragma unroll
        for (int r = 0; r < 4; ++r) {
            const float lr = __shfl(l, (lane & 48) | (quad * 4 + r));
            const float inv_l = 1.0f / fmaxf(lr, 1e-30f);
            const int row = row_base + quad * 4 + r;
            float* op = outg + ((size_t)b * SEQ + row) * (NH * HD) + h * HD;
            #pragma unroll
            for (int c = 0; c < 4; ++c) {
                float val = o[c][r] * inv_l;
                unsigned bits = __builtin_bit_cast(unsigned, val);
                if ((bits & 0x7F800000u) == 0x7F800000u) val = 0.0f;  // scrub inf/NaN
                op[c * 16 + l16] = val;
            }
        }
    };
    store_o(oA, lA, q0 + wave * 16);
    store_o(oB, lB, q0 + 64 + wave * 16);
}

extern "C" void kernel_launch(void* const* d_in, const int* in_sizes, int n_in,
                              void* d_out, int out_size, void* d_ws, size_t ws_size,
                              hipStream_t stream) {
    const float* q = (const float*)d_in[0];
    const float* k = (const float*)d_in[1];
    const float* v = (const float*)d_in[2];
    float* out = (float*)d_out;
    dim3 grid(NB * NH, SEQ / BQ);   // x = bh, y = q-block (reversed in-kernel: heavy first)
    fa_fwd<<<grid, 256, 0, stream>>>(q, k, v, out);
}